// Round 1
// baseline (135.940 us; speedup 1.0000x reference)
//
#include <hip/hip_runtime.h>
#include <hip/hip_bf16.h>

// Problem constants (from reference)
#define NV   100      // n_vars (output cols)
#define NVP  112      // padded to 7 x 16 MFMA n-tiles
#define HID  64       // hidden per expert (K per expert)
#define NE   1000     // experts
#define NB   4096     // batch (M)
#define LDW  72       // LDS/ws row stride in u16 for [v][hh] tile (64 + 8 pad -> bank spread)
#define ESPLIT 32     // K-split across blockIdx.y
#define EPB  32       // experts per split (ceil(1000/32))

typedef __attribute__((ext_vector_type(8))) short short8;   // 8 x bf16 (4 VGPR) MFMA operand
typedef __attribute__((ext_vector_type(4))) float f32x4;    // MFMA accumulator

__device__ float g_bsum[NV];   // sum_e b2[e][v], recomputed every call (deterministic)

__device__ __forceinline__ unsigned short f2bf(float f) {
    union { float f; unsigned u; } v; v.f = f;
    unsigned r = v.u + 0x7fffu + ((v.u >> 16) & 1u);   // RNE to bf16
    return (unsigned short)(r >> 16);
}

// ---------------- bias: g_bsum[v] = sum_e b2[e*NV + v] ----------------
__global__ void bias_kernel(const float* __restrict__ b2) {
    int v = blockIdx.x;
    float s = 0.f;
    for (int e = threadIdx.x; e < NE; e += 256)
        s += b2[e * NV + v];
    __shared__ float red[4];
    for (int off = 32; off; off >>= 1) s += __shfl_down(s, off, 64);
    if ((threadIdx.x & 63) == 0) red[threadIdx.x >> 6] = s;
    __syncthreads();
    if (threadIdx.x == 0) g_bsum[v] = red[0] + red[1] + red[2] + red[3];
}

// ---------------- init (atomic fallback path): out = bsum broadcast ----------------
__global__ void init_kernel(float* __restrict__ out) {
    int idx = blockIdx.x * 256 + threadIdx.x;
    if (idx < NB * NV) out[idx] = g_bsum[idx % NV];
}

// ---------------- prepass: W2 [e][hh][v] f32 -> ws [e][v][hh] bf16, LDW=72 pad ----------------
// expert stride in ws = 16384 B (112*72*2 = 16128, padded to 16 KiB for clean copies)
__global__ void prepass_kernel(const float* __restrict__ W2, unsigned* __restrict__ w2bf) {
    int e = blockIdx.x;
    int v = threadIdx.x;             // 128 threads, v < 100 active
    if (v >= NV) return;
    const float* src = W2 + (size_t)e * (HID * NV) + v;
    unsigned* dst = w2bf + (size_t)e * 4096 + v * (LDW / 2);   // u32 units
    #pragma unroll
    for (int hh2 = 0; hh2 < 32; ++hh2) {
        float f0 = src[(2 * hh2) * NV];
        float f1 = src[(2 * hh2 + 1) * NV];
        dst[hh2] = (unsigned)f2bf(f0) | ((unsigned)f2bf(f1) << 16);
    }
}

// ---------------- main fused kernel ----------------
// grid (32 Mblocks, 32 Ksplits), 256 threads (4 waves), wave owns 32 rows (2 x 16-row A frags)
template<bool BF16WS, bool PART>
__global__ __launch_bounds__(256, 3) void moe_main(
    const float* __restrict__ x, const float* __restrict__ W1,
    const float* __restrict__ b1, const float* __restrict__ W2,
    const unsigned* __restrict__ w2bf, float* __restrict__ dst)
{
    __shared__ unsigned short w2t[8192];    // 16 KiB: [v][LDW] bf16 tile of current expert

    const int tid  = threadIdx.x;
    const int lane = tid & 63;
    const int wave = tid >> 6;
    const int lrow = lane & 15;     // A row / B col / D col within fragment
    const int kg   = lane >> 4;     // k-group (assumed k = kg*8 + j, same map for A and B)

    const int row0 = blockIdx.x * 128 + wave * 32;
    const int e0 = blockIdx.y * EPB;
    const int e1 = min(NE, e0 + EPB);

    f32x4 acc[2][7];
    #pragma unroll
    for (int rf = 0; rf < 2; ++rf)
        #pragma unroll
        for (int t = 0; t < 7; ++t)
            acc[rf][t] = (f32x4){0.f, 0.f, 0.f, 0.f};

    const float* xr0 = x + (size_t)(row0 + lrow) * NE;
    const float* xr1 = x + (size_t)(row0 + 16 + lrow) * NE;

    for (int e = e0; e < e1; ++e) {
        __syncthreads();   // protect previous tile's readers
        if (BF16WS) {
            // straight 16 KiB linear copy ws -> LDS, 16 B per lane per iter
            const unsigned* g = w2bf + (size_t)e * 4096;
            #pragma unroll
            for (int k = 0; k < 4; ++k) {
                int off16 = k * 256 + tid;   // 16-byte unit index
                __builtin_amdgcn_global_load_lds(
                    (const __attribute__((address_space(1))) unsigned*)(g + off16 * 4),
                    (__attribute__((address_space(3))) unsigned*)((unsigned*)w2t + off16 * 4),
                    16, 0, 0);
            }
        } else {
            // fp32 global -> bf16 LDS transpose; i-decode chosen so LDS u32 writes are 2-way (free)
            const float* src = W2 + (size_t)e * (HID * NV);
            unsigned* w2t32 = (unsigned*)w2t;
            #pragma unroll
            for (int k = 0; k < 13; ++k) {
                int i = tid + k * 256;
                if (i < (HID / 2) * NV) {          // 3200 packed writes
                    int a3  = i / 400;             // hh2 high bits
                    int rem = i - a3 * 400;
                    int bv  = rem >> 2;            // v
                    int c   = rem & 3;             // hh2 low bits
                    int hh2 = a3 * 4 + c;
                    float f0 = src[(2 * hh2) * NV + bv];
                    float f1 = src[(2 * hh2 + 1) * NV + bv];
                    w2t32[bv * (LDW / 2) + hh2] =
                        (unsigned)f2bf(f0) | ((unsigned)f2bf(f1) << 16);
                }
            }
        }
        __syncthreads();

        float xv0 = xr0[e];
        float xv1 = xr1[e];
        const float* w1p = W1 + e * HID;
        const float* b1p = b1 + e * HID;
        #pragma unroll
        for (int ks = 0; ks < 2; ++ks) {
            const int hb = ks * 32 + kg * 8;
            f32x4 w1lo = *(const f32x4*)(w1p + hb);
            f32x4 w1hi = *(const f32x4*)(w1p + hb + 4);
            f32x4 blo  = *(const f32x4*)(b1p + hb);
            f32x4 bhi  = *(const f32x4*)(b1p + hb + 4);
            short8 a0, a1;
            #pragma unroll
            for (int j = 0; j < 4; ++j) {
                a0[j]     = (short)f2bf(fmaxf(fmaf(xv0, w1lo[j], blo[j]), 0.f));
                a0[j + 4] = (short)f2bf(fmaxf(fmaf(xv0, w1hi[j], bhi[j]), 0.f));
                a1[j]     = (short)f2bf(fmaxf(fmaf(xv1, w1lo[j], blo[j]), 0.f));
                a1[j + 4] = (short)f2bf(fmaxf(fmaf(xv1, w1hi[j], bhi[j]), 0.f));
            }
            #pragma unroll
            for (int t = 0; t < 7; ++t) {
                // b-frag: 8 consecutive bf16 along hh at col v = t*16+lrow -> one ds_read_b128
                short8 bf = *(const short8*)&w2t[(t * 16 + lrow) * LDW + hb];
                acc[0][t] = __builtin_amdgcn_mfma_f32_16x16x32_bf16(a0, bf, acc[0][t], 0, 0, 0);
                acc[1][t] = __builtin_amdgcn_mfma_f32_16x16x32_bf16(a1, bf, acc[1][t], 0, 0, 0);
            }
        }
    }

    // epilogue: C/D layout col = lane&15, row = kg*4 + reg  [verified m89/m91]
    #pragma unroll
    for (int rf = 0; rf < 2; ++rf) {
        #pragma unroll
        for (int t = 0; t < 7; ++t) {
            int col = t * 16 + lrow;
            if (col < NV) {
                size_t base = (size_t)(row0 + rf * 16 + kg * 4) * NV + col;
                if (PART) {
                    float* p = dst + (size_t)blockIdx.y * (NB * NV);
                    #pragma unroll
                    for (int r = 0; r < 4; ++r)
                        p[base + (size_t)r * NV] = acc[rf][t][r];
                } else {
                    #pragma unroll
                    for (int r = 0; r < 4; ++r)
                        atomicAdd(&dst[base + (size_t)r * NV], acc[rf][t][r]);
                }
            }
        }
    }
}

// ---------------- reduce partials + bias -> out ----------------
__global__ void reduce_kernel(const float* __restrict__ part, float* __restrict__ out) {
    int idx = blockIdx.x * 256 + threadIdx.x;
    if (idx >= NB * NV) return;
    float s = g_bsum[idx % NV];
    #pragma unroll 8
    for (int k = 0; k < ESPLIT; ++k)
        s += part[(size_t)k * (NB * NV) + idx];
    out[idx] = s;
}

extern "C" void kernel_launch(void* const* d_in, const int* in_sizes, int n_in,
                              void* d_out, int out_size, void* d_ws, size_t ws_size,
                              hipStream_t stream) {
    const float* x  = (const float*)d_in[0];
    const float* W1 = (const float*)d_in[1];
    const float* b1 = (const float*)d_in[2];
    const float* W2 = (const float*)d_in[3];
    const float* b2 = (const float*)d_in[4];
    float* out = (float*)d_out;

    const size_t W2BF_BYTES = (size_t)NE * 16384;              // 16,384,000
    const size_t PART_BYTES = (size_t)ESPLIT * NB * NV * 4;    // 52,428,800

    bias_kernel<<<NV, 256, 0, stream>>>(b2);

    bool hasBF = false, hasPart = false;
    unsigned* w2bf = nullptr; float* part = nullptr;
    if (ws_size >= W2BF_BYTES + PART_BYTES) {
        hasBF = true; hasPart = true;
        w2bf = (unsigned*)d_ws;
        part = (float*)((char*)d_ws + W2BF_BYTES);
    } else if (ws_size >= PART_BYTES) {
        hasPart = true; part = (float*)d_ws;
    } else if (ws_size >= W2BF_BYTES) {
        hasBF = true; w2bf = (unsigned*)d_ws;
    }

    if (hasBF)    prepass_kernel<<<NE, 128, 0, stream>>>(W2, w2bf);
    if (!hasPart) init_kernel<<<(NB * NV + 255) / 256, 256, 0, stream>>>(out);

    dim3 grid(NB / 128, ESPLIT);
    if (hasBF && hasPart)
        moe_main<true, true><<<grid, 256, 0, stream>>>(x, W1, b1, W2, w2bf, part);
    else if (!hasBF && hasPart)
        moe_main<false, true><<<grid, 256, 0, stream>>>(x, W1, b1, W2, nullptr, part);
    else if (hasBF)
        moe_main<true, false><<<grid, 256, 0, stream>>>(x, W1, b1, W2, w2bf, out);
    else
        moe_main<false, false><<<grid, 256, 0, stream>>>(x, W1, b1, W2, nullptr, out);

    if (hasPart)
        reduce_kernel<<<(NB * NV + 255) / 256, 256, 0, stream>>>(part, out);
}

// Round 3
// 103.611 us; speedup vs baseline: 1.3120x; 1.3120x over previous
//
#include <hip/hip_runtime.h>
#include <hip/hip_bf16.h>

#define NV 100       // n_vars
#define HID 64       // hidden
#define NE 1000      // experts
#define NB 4096      // batch
#define LDW 72       // u16 stride of one w2bf row [v][h] (64 + 8 pad)
#define ESPLIT 32    // K-split count

typedef __attribute__((ext_vector_type(8))) short short8;   // MFMA A/B frag
typedef __attribute__((ext_vector_type(4))) float f32x4;    // MFMA C/D frag
typedef __attribute__((ext_vector_type(4))) unsigned u32x4;

__device__ __align__(16) float g_bsum[NV];

__device__ __forceinline__ unsigned short f2bf(float f) {
    union { float f; unsigned u; } v; v.f = f;
    unsigned r = v.u + 0x7fffu + ((v.u >> 16) & 1u);   // RNE
    return (unsigned short)(r >> 16);
}
__device__ __forceinline__ float bf2f(unsigned short s) {
    union { unsigned u; float f; } v; v.u = ((unsigned)s) << 16;
    return v.f;
}
__device__ __forceinline__ unsigned pkbf(float a, float b) {
    return (unsigned)f2bf(a) | ((unsigned)f2bf(b) << 16);
}

// balanced, 4-aligned expert split: 26 splits of 32, 6 splits of 28
__device__ __host__ __forceinline__ void esplit_range(int ks, int* pe0, int* pne) {
    int e0 = (ks < 26) ? 32 * ks : 832 + 28 * (ks - 26);
    int ne = (ks < 26) ? 32 : 28;
    *pe0 = e0; *pne = ne;
}

// ---------------- bias: g_bsum[v] = sum_e b2[e*NV + v] ----------------
__global__ void bias_kernel(const float* __restrict__ b2) {
    int v = blockIdx.x;
    float s = 0.f;
    for (int e = threadIdx.x; e < NE; e += 256)
        s += b2[e * NV + v];
    __shared__ float red[4];
    for (int off = 32; off; off >>= 1) s += __shfl_down(s, off, 64);
    if ((threadIdx.x & 63) == 0) red[threadIdx.x >> 6] = s;
    __syncthreads();
    if (threadIdx.x == 0) g_bsum[v] = red[0] + red[1] + red[2] + red[3];
}

// ---------------- init (fallback path): out = bsum broadcast ----------------
__global__ void init_kernel(float* __restrict__ out) {
    int idx = blockIdx.x * 256 + threadIdx.x;
    if (idx < NB * NV) out[idx] = g_bsum[idx % NV];
}

// ---------------- prepass v2: coalesced W2 -> bf16 [e][v][LDW] via LDS transpose ----------------
__global__ void prepass2(const float* __restrict__ W2, unsigned* __restrict__ w2bf) {
    __shared__ float t[HID][NV + 1];
    int e = blockIdx.x;
    const float* src = W2 + (size_t)e * (HID * NV);
    for (int i = threadIdx.x; i < HID * NV; i += 256) {
        int hh = i / NV;
        int v = i - hh * NV;
        t[hh][v] = src[i];
    }
    __syncthreads();
    unsigned* dst = w2bf + (size_t)e * 4096;
    for (int o = threadIdx.x; o < 4096; o += 256) {
        int v = o / 36;
        int c = o - v * 36;
        unsigned val = 0;
        if (v < NV && c < 32)
            val = pkbf(t[2 * c][v], t[2 * c + 1][v]);
        dst[o] = val;
    }
}

// ---------------- main: BM=256, 8 waves, double-buffered W2, LDS-only inner loop ----------------
__global__ __launch_bounds__(512, 4) void moe2(
    const float* __restrict__ x, const float* __restrict__ W1,
    const float* __restrict__ b1, const unsigned* __restrict__ w2bf,
    float* __restrict__ part)
{
    __shared__ __align__(16) unsigned char smem[57344];
    // [0,32768): W2 tile double buffer, 2 x 16 KiB, bf16 [v][LDW]
    unsigned short* xts = (unsigned short*)(smem + 32768);   // [32][256] bf16 x^T tile
    unsigned short* w1l = (unsigned short*)(smem + 49152);   // [32][64] bf16
    unsigned short* b1l = (unsigned short*)(smem + 53248);   // [32][64] bf16

    const int bid = blockIdx.x;
    const int xcd = bid & 7;
    const int jj  = bid >> 3;              // 0..63
    const int ks  = xcd * 4 + (jj & 3);    // ksplit: 4 consecutive per XCD (L2 locality)
    const int mb  = jj >> 2;               // 0..15

    const int tid  = threadIdx.x;
    const int lane = tid & 63;
    const int wave = tid >> 6;             // 0..7
    const int lrow = lane & 15;
    const int kg   = lane >> 4;

    const int row0 = mb * 256;
    int e0, ne; esplit_range(ks, &e0, &ne);

    // ---- stage x tile: x[row0+r][e0+eb..] -> xts[eb][r] bf16 (coalesced read) ----
    {
        const int r = tid >> 1;
        const int h = tid & 1;
        const float* xp = x + (size_t)(row0 + r) * NE + e0;
        #pragma unroll
        for (int c4 = 0; c4 < 4; ++c4) {
            int eb = h * 16 + c4 * 4;
            if (eb < ne) {
                float4 v = *(const float4*)(xp + eb);
                xts[(eb + 0) * 256 + r] = f2bf(v.x);
                xts[(eb + 1) * 256 + r] = f2bf(v.y);
                xts[(eb + 2) * 256 + r] = f2bf(v.z);
                xts[(eb + 3) * 256 + r] = f2bf(v.w);
            }
        }
    }
    // ---- stage W1/b1 bf16 [e][64] (coalesced) ----
    {
        int i = tid * 4;                 // u16 index into [32][64]
        int e = i >> 6, h = i & 63;
        if (e < ne) {
            float4 wv = *(const float4*)(W1 + (size_t)(e0 + e) * HID + h);
            float4 bv = *(const float4*)(b1 + (size_t)(e0 + e) * HID + h);
            *(unsigned*)&w1l[i]     = pkbf(wv.x, wv.y);
            *(unsigned*)&w1l[i + 2] = pkbf(wv.z, wv.w);
            *(unsigned*)&b1l[i]     = pkbf(bv.x, bv.y);
            *(unsigned*)&b1l[i + 2] = pkbf(bv.z, bv.w);
        }
    }

    // ---- W2 staging: 16 KiB linear global_load_lds copy ----
    auto stage_w2 = [&](int buf, int e) {
        const unsigned* g = w2bf + (size_t)e * 4096;
        unsigned* lbase = (unsigned*)(smem + buf * 16384);
        #pragma unroll
        for (int k = 0; k < 2; ++k) {
            int off16 = k * 512 + tid;
            __builtin_amdgcn_global_load_lds(
                (const __attribute__((address_space(1))) unsigned*)(g + off16 * 4),
                (__attribute__((address_space(3))) unsigned*)(lbase + off16 * 4),
                16, 0, 0);
        }
    };

    stage_w2(0, e0);
    __syncthreads();   // drains vmcnt(0)+lgkmcnt(0): buf0 + x + w1/b1 ready

    f32x4 acc[2][7];
    #pragma unroll
    for (int rf = 0; rf < 2; ++rf)
        #pragma unroll
        for (int t = 0; t < 7; ++t)
            acc[rf][t] = (f32x4){0.f, 0.f, 0.f, 0.f};

    const int xrow = wave * 32 + lrow;
    int cur = 0;
    for (int ei = 0; ei < ne; ++ei) {
        if (ei + 1 < ne) stage_w2(cur ^ 1, e0 + ei + 1);   // prefetch next expert

        float xv0 = bf2f(xts[ei * 256 + xrow]);
        float xv1 = bf2f(xts[ei * 256 + xrow + 16]);
        const unsigned short* w2c = (const unsigned short*)(smem + cur * 16384);

        #pragma unroll
        for (int ksh = 0; ksh < 2; ++ksh) {
            const int hb = ksh * 32 + kg * 8;
            u32x4 wq = *(const u32x4*)&w1l[ei * 64 + hb];   // broadcast b128
            u32x4 bq = *(const u32x4*)&b1l[ei * 64 + hb];
            short8 a0, a1;
            unsigned* a0u = (unsigned*)&a0;
            unsigned* a1u = (unsigned*)&a1;
            #pragma unroll
            for (int q = 0; q < 4; ++q) {
                float wL = __builtin_bit_cast(float, wq[q] << 16);
                float wH = __builtin_bit_cast(float, wq[q] & 0xffff0000u);
                float bL = __builtin_bit_cast(float, bq[q] << 16);
                float bH = __builtin_bit_cast(float, bq[q] & 0xffff0000u);
                a0u[q] = pkbf(fmaxf(fmaf(xv0, wL, bL), 0.f),
                              fmaxf(fmaf(xv0, wH, bH), 0.f));
                a1u[q] = pkbf(fmaxf(fmaf(xv1, wL, bL), 0.f),
                              fmaxf(fmaf(xv1, wH, bH), 0.f));
            }
            #pragma unroll
            for (int t = 0; t < 7; ++t) {
                short8 bf = *(const short8*)&w2c[(t * 16 + lrow) * LDW + hb];
                acc[0][t] = __builtin_amdgcn_mfma_f32_16x16x32_bf16(a0, bf, acc[0][t], 0, 0, 0);
                acc[1][t] = __builtin_amdgcn_mfma_f32_16x16x32_bf16(a1, bf, acc[1][t], 0, 0, 0);
            }
        }
        __syncthreads();   // drains vmcnt(0): next buffer landed during compute
        cur ^= 1;
    }

    // epilogue: C/D layout col = lane&15, row = kg*4 + reg
    float* dst = part + (size_t)ks * (NB * NV);
    #pragma unroll
    for (int rf = 0; rf < 2; ++rf) {
        #pragma unroll
        for (int t = 0; t < 7; ++t) {
            int col = t * 16 + lrow;
            if (col < NV) {
                size_t base = (size_t)(row0 + wave * 32 + rf * 16 + kg * 4) * NV + col;
                #pragma unroll
                for (int r = 0; r < 4; ++r)
                    dst[base + (size_t)r * NV] = acc[rf][t][r];
            }
        }
    }
}

// ---------------- fallback (tiny ws): in-kernel convert + atomics (round-1 proven) ----------------
__global__ __launch_bounds__(256, 3) void moe_fallback(
    const float* __restrict__ x, const float* __restrict__ W1,
    const float* __restrict__ b1, const float* __restrict__ W2,
    float* __restrict__ dst)
{
    __shared__ unsigned short w2t[8192];
    const int tid  = threadIdx.x;
    const int lane = tid & 63;
    const int wave = tid >> 6;
    const int lrow = lane & 15;
    const int kg   = lane >> 4;
    const int row0 = blockIdx.x * 128 + wave * 32;
    const int e0 = blockIdx.y * 32;
    const int e1 = min(NE, e0 + 32);

    f32x4 acc[2][7];
    #pragma unroll
    for (int rf = 0; rf < 2; ++rf)
        #pragma unroll
        for (int t = 0; t < 7; ++t)
            acc[rf][t] = (f32x4){0.f, 0.f, 0.f, 0.f};

    const float* xr0 = x + (size_t)(row0 + lrow) * NE;
    const float* xr1 = x + (size_t)(row0 + 16 + lrow) * NE;

    for (int e = e0; e < e1; ++e) {
        __syncthreads();
        const float* src = W2 + (size_t)e * (HID * NV);
        unsigned* w2t32 = (unsigned*)w2t;
        #pragma unroll
        for (int k = 0; k < 13; ++k) {
            int i = tid + k * 256;
            if (i < (HID / 2) * NV) {
                int a3  = i / 400;
                int rem = i - a3 * 400;
                int bv  = rem >> 2;
                int c   = rem & 3;
                int hh2 = a3 * 4 + c;
                float f0 = src[(2 * hh2) * NV + bv];
                float f1 = src[(2 * hh2 + 1) * NV + bv];
                w2t32[bv * (LDW / 2) + hh2] = pkbf(f0, f1);
            }
        }
        __syncthreads();

        float xv0 = xr0[e];
        float xv1 = xr1[e];
        const float* w1p = W1 + e * HID;
        const float* b1p = b1 + e * HID;
        #pragma unroll
        for (int ksh = 0; ksh < 2; ++ksh) {
            const int hb = ksh * 32 + kg * 8;
            f32x4 w1lo = *(const f32x4*)(w1p + hb);
            f32x4 w1hi = *(const f32x4*)(w1p + hb + 4);
            f32x4 blo  = *(const f32x4*)(b1p + hb);
            f32x4 bhi  = *(const f32x4*)(b1p + hb + 4);
            short8 a0, a1;
            unsigned* a0u = (unsigned*)&a0;
            unsigned* a1u = (unsigned*)&a1;
            #pragma unroll
            for (int q = 0; q < 2; ++q) {
                a0u[q]     = pkbf(fmaxf(fmaf(xv0, w1lo[2*q], blo[2*q]), 0.f),
                                  fmaxf(fmaf(xv0, w1lo[2*q+1], blo[2*q+1]), 0.f));
                a0u[q + 2] = pkbf(fmaxf(fmaf(xv0, w1hi[2*q], bhi[2*q]), 0.f),
                                  fmaxf(fmaf(xv0, w1hi[2*q+1], bhi[2*q+1]), 0.f));
                a1u[q]     = pkbf(fmaxf(fmaf(xv1, w1lo[2*q], blo[2*q]), 0.f),
                                  fmaxf(fmaf(xv1, w1lo[2*q+1], blo[2*q+1]), 0.f));
                a1u[q + 2] = pkbf(fmaxf(fmaf(xv1, w1hi[2*q], bhi[2*q]), 0.f),
                                  fmaxf(fmaf(xv1, w1hi[2*q+1], bhi[2*q+1]), 0.f));
            }
            #pragma unroll
            for (int t = 0; t < 7; ++t) {
                short8 bf = *(const short8*)&w2t[(t * 16 + lrow) * LDW + hb];
                acc[0][t] = __builtin_amdgcn_mfma_f32_16x16x32_bf16(a0, bf, acc[0][t], 0, 0, 0);
                acc[1][t] = __builtin_amdgcn_mfma_f32_16x16x32_bf16(a1, bf, acc[1][t], 0, 0, 0);
            }
        }
    }

    #pragma unroll
    for (int rf = 0; rf < 2; ++rf) {
        #pragma unroll
        for (int t = 0; t < 7; ++t) {
            int col = t * 16 + lrow;
            if (col < NV) {
                size_t base = (size_t)(row0 + rf * 16 + kg * 4) * NV + col;
                #pragma unroll
                for (int r = 0; r < 4; ++r)
                    atomicAdd(&dst[base + (size_t)r * NV], acc[rf][t][r]);
            }
        }
    }
}

// ---------------- reduce: out = bias + sum_k part[k] (float4) ----------------
__global__ void reduce2(const float* __restrict__ part, float* __restrict__ out) {
    int i4 = blockIdx.x * 256 + threadIdx.x;   // < NB*NV/4 = 102400
    f32x4 s = *(const f32x4*)&g_bsum[(i4 % 25) * 4];
    size_t off = (size_t)i4 * 4;
    #pragma unroll 4
    for (int k = 0; k < ESPLIT; ++k)
        s += *(const f32x4*)&part[(size_t)k * (NB * NV) + off];
    *(f32x4*)&out[off] = s;
}

extern "C" void kernel_launch(void* const* d_in, const int* in_sizes, int n_in,
                              void* d_out, int out_size, void* d_ws, size_t ws_size,
                              hipStream_t stream) {
    const float* x  = (const float*)d_in[0];
    const float* W1 = (const float*)d_in[1];
    const float* b1 = (const float*)d_in[2];
    const float* W2 = (const float*)d_in[3];
    const float* b2 = (const float*)d_in[4];
    float* out = (float*)d_out;

    const size_t W2BF_BYTES = (size_t)NE * 16384;            // 16,384,000
    const size_t PART_BYTES = (size_t)ESPLIT * NB * NV * 4;  // 52,428,800

    bias_kernel<<<NV, 256, 0, stream>>>(b2);

    if (ws_size >= W2BF_BYTES + PART_BYTES) {
        unsigned* w2bf = (unsigned*)d_ws;
        float* part = (float*)((char*)d_ws + W2BF_BYTES);
        prepass2<<<NE, 256, 0, stream>>>(W2, w2bf);
        moe2<<<512, 512, 0, stream>>>(x, W1, b1, w2bf, part);
        reduce2<<<(NB * NV / 4 + 255) / 256, 256, 0, stream>>>(part, out);
    } else {
        init_kernel<<<(NB * NV + 255) / 256, 256, 0, stream>>>(out);
        moe_fallback<<<dim3(NB / 128, ESPLIT), 256, 0, stream>>>(x, W1, b1, W2, out);
    }
}